// Round 1
// baseline (9145.619 us; speedup 1.0000x reference)
//
#include <hip/hip_runtime.h>
#include <hip/hip_bf16.h>

#define N_CHAR 128
#define EMBED  256
#define HIDDEN 1024
#define BATCH  64
#define SEQ    512

// ---------------------------------------------------------------------------
// P[c][j] = sum_k embeddings[c][k] * W_ih[j][k]   (128 x 1024)
// grid 512, block 256: block bi -> c = bi>>2, j = (bi&3)*256 + tid
// ---------------------------------------------------------------------------
__global__ void pk(const float* __restrict__ emb, const float* __restrict__ Wih,
                   float* __restrict__ P) {
  __shared__ float e[EMBED];
  const int c = blockIdx.x >> 2;
  const int j = ((blockIdx.x & 3) << 8) + threadIdx.x;
  if (threadIdx.x < EMBED / 4) {
    reinterpret_cast<float4*>(e)[threadIdx.x] =
        reinterpret_cast<const float4*>(emb + c * EMBED)[threadIdx.x];
  }
  __syncthreads();
  const float4* w = reinterpret_cast<const float4*>(Wih + j * EMBED);
  float acc = 0.f;
#pragma unroll 8
  for (int k4 = 0; k4 < EMBED / 4; ++k4) {
    const float4 wv = w[k4];
    const float4 ev = reinterpret_cast<const float4*>(e)[k4];
    acc += wv.x * ev.x + wv.y * ev.y + wv.z * ev.z + wv.w * ev.w;
  }
  P[c * HIDDEN + j] = acc;
}

// ---------------------------------------------------------------------------
// h[b][j] = h0[j]  (broadcast init)
// ---------------------------------------------------------------------------
__global__ void initk(const float* __restrict__ h0, float* __restrict__ h) {
  const int i = blockIdx.x * blockDim.x + threadIdx.x;  // 65536 threads
  h[i] = h0[i & (HIDDEN - 1)];
}

// ---------------------------------------------------------------------------
// One recurrence step:
//   h_out[b][j] = tanh( P[t[b][s]][j] + sum_k h_in[b][k] * W_hh[j][k] )
// grid = HIDDEN/4 = 256 blocks, block = 256 threads.
// Block owns j-tile of 4 rows x all 64 batch rows; thread = one (b, j) output.
//   tid: b = tid>>2 (0..63), jj = tid&3.
// h and W tiles staged through LDS in 64-wide k chunks.
// LDS rows padded to 68 floats: float4 reads land on distinct bank quads
// ((4b+k)%32 -> at most 2-way, free per m136).
// ---------------------------------------------------------------------------
__global__ void __launch_bounds__(256) stepk(
    const float* __restrict__ h_in, float* __restrict__ h_out,
    const float* __restrict__ Whh, const float* __restrict__ P,
    const int* __restrict__ t, int s) {
  __shared__ float hs[BATCH][68];  // 64 x 64 chunk of h (+4 pad)
  __shared__ float ws[4][68];      // 4 x 64 chunk of W_hh j-tile

  const int tid = threadIdx.x;
  const int j0 = blockIdx.x * 4;
  const int b = tid >> 2;
  const int jj = tid & 3;

  float acc = 0.f;

  for (int kc = 0; kc < HIDDEN; kc += 64) {
    __syncthreads();  // protect previous chunk's LDS reads
    // stage h chunk: 64 rows x 64 floats = 1024 float4; 4 per thread
#pragma unroll
    for (int i = 0; i < 4; ++i) {
      const int v = tid + 256 * i;      // 0..1023 (float4 slot)
      const int row = v >> 4;           // 16 float4 per row
      const int col = (v & 15) * 4;
      *reinterpret_cast<float4*>(&hs[row][col]) =
          *reinterpret_cast<const float4*>(&h_in[row * HIDDEN + kc + col]);
    }
    // stage W tile: 4 rows x 64 floats, one scalar per thread (coalesced)
    {
      const int wr = tid >> 6;
      const int wk = tid & 63;
      ws[wr][wk] = Whh[(j0 + wr) * HIDDEN + kc + wk];
    }
    __syncthreads();
#pragma unroll
    for (int k = 0; k < 64; k += 4) {
      const float4 hv = *reinterpret_cast<const float4*>(&hs[b][k]);
      const float4 wv = *reinterpret_cast<const float4*>(&ws[jj][k]);
      acc += hv.x * wv.x + hv.y * wv.y + hv.z * wv.z + hv.w * wv.w;
    }
  }

  const int c = t[b * SEQ + s];
  const float pre = P[c * HIDDEN + j0 + jj] + acc;
  h_out[b * HIDDEN + j0 + jj] = tanhf(pre);
}

// ---------------------------------------------------------------------------
// out[b][c] = sum_k h[b][k] * W_proj[c][k] + b_proj[c]   (64 x 128)
// grid 64 (one block per b), block 128 (one thread per c)
// ---------------------------------------------------------------------------
__global__ void outk(const float* __restrict__ h, const float* __restrict__ Wp,
                     const float* __restrict__ bp, float* __restrict__ out) {
  __shared__ float hb[HIDDEN];
  const int b = blockIdx.x;
  const int c = threadIdx.x;
  for (int i = threadIdx.x; i < HIDDEN / 4; i += blockDim.x) {
    reinterpret_cast<float4*>(hb)[i] =
        reinterpret_cast<const float4*>(h + b * HIDDEN)[i];
  }
  __syncthreads();
  const float4* w = reinterpret_cast<const float4*>(Wp + c * HIDDEN);
  float acc = 0.f;
#pragma unroll 8
  for (int k4 = 0; k4 < HIDDEN / 4; ++k4) {
    const float4 wv = w[k4];
    const float4 hv = reinterpret_cast<const float4*>(hb)[k4];
    acc += wv.x * hv.x + wv.y * hv.y + wv.z * hv.z + wv.w * hv.w;
  }
  out[b * N_CHAR + c] = acc + bp[c];
}

// ---------------------------------------------------------------------------
extern "C" void kernel_launch(void* const* d_in, const int* in_sizes, int n_in,
                              void* d_out, int out_size, void* d_ws, size_t ws_size,
                              hipStream_t stream) {
  const int*   t   = (const int*)d_in[0];
  const float* emb = (const float*)d_in[1];
  const float* Wih = (const float*)d_in[2];
  const float* Whh = (const float*)d_in[3];
  const float* h0  = (const float*)d_in[4];
  const float* Wp  = (const float*)d_in[5];
  const float* bp  = (const float*)d_in[6];
  float* out = (float*)d_out;

  float* P  = (float*)d_ws;                 // 128*1024
  float* ha = P + N_CHAR * HIDDEN;          // 64*1024
  float* hb = ha + BATCH * HIDDEN;          // 64*1024

  pk<<<512, 256, 0, stream>>>(emb, Wih, P);
  initk<<<(BATCH * HIDDEN) / 256, 256, 0, stream>>>(h0, ha);

  float* bufs[2] = {ha, hb};
  for (int s = 0; s < SEQ; ++s) {
    stepk<<<HIDDEN / 4, 256, 0, stream>>>(bufs[s & 1], bufs[(s + 1) & 1], Whh,
                                          P, t, s);
  }
  // SEQ is even -> final state is in bufs[0]
  outk<<<BATCH, 128, 0, stream>>>(bufs[0], Wp, bp, out);
}

// Round 2
// 3581.739 us; speedup vs baseline: 2.5534x; 2.5534x over previous
//
#include <hip/hip_runtime.h>
#include <hip/hip_bf16.h>

#define N_CHAR 128
#define EMBED  256
#define HIDDEN 1024
#define BATCH  64
#define SEQ    512

__device__ __forceinline__ float dot4(const float4 a, const float4 b) {
  return a.x * b.x + a.y * b.y + a.z * b.z + a.w * b.w;
}

// ---------------------------------------------------------------------------
// P[c][j] = sum_k embeddings[c][k] * W_ih[j][k]   (128 x 1024)
// ---------------------------------------------------------------------------
__global__ void pk(const float* __restrict__ emb, const float* __restrict__ Wih,
                   float* __restrict__ P) {
  __shared__ float e[EMBED];
  const int c = blockIdx.x >> 2;
  const int j = ((blockIdx.x & 3) << 8) + threadIdx.x;
  if (threadIdx.x < EMBED / 4) {
    reinterpret_cast<float4*>(e)[threadIdx.x] =
        reinterpret_cast<const float4*>(emb + c * EMBED)[threadIdx.x];
  }
  __syncthreads();
  const float4* w = reinterpret_cast<const float4*>(Wih + j * EMBED);
  float acc = 0.f;
#pragma unroll 8
  for (int k4 = 0; k4 < EMBED / 4; ++k4)
    acc += dot4(w[k4], reinterpret_cast<const float4*>(e)[k4]);
  P[c * HIDDEN + j] = acc;
}

// ---------------------------------------------------------------------------
// h[b][j] = h0[j]
// ---------------------------------------------------------------------------
__global__ void initk(const float* __restrict__ h0v, float* __restrict__ h) {
  const int i = blockIdx.x * blockDim.x + threadIdx.x;
  h[i] = h0v[i & (HIDDEN - 1)];
}

// ---------------------------------------------------------------------------
// One recurrence step: h_out[b][j] = tanh(P[t[b][s]][j] + sum_k h_in[b][k]*W_hh[j][k])
//
// Grid 256 = (4 b-tiles of 16) x (64 j-tiles of 16); block 256 threads.
// Thread (jg = tid>>6, ks = tid&63):
//   - owns W[j0+4*jg+jj][k] for jj<4, k in {4*ks+256*q+r : q<4, r<4}  (64 VGPRs)
//   - accumulates partial dots for all 16 b's of the tile        (64 VGPRs)
// h read straight from global (coalesced float4; block slice 64KB -> L1/L2).
// Cross-lane (ks) reduction via 64KB LDS partial buffer, finished by wave 0.
// ---------------------------------------------------------------------------
__global__ void __launch_bounds__(256) stepk(
    const float* __restrict__ h_in, float* __restrict__ h_out,
    const float* __restrict__ Whh, const float* __restrict__ P,
    const int* __restrict__ t, int s) {
  __shared__ float4 part[4 * 16 * 64];  // [jg][bl][ks] -> float4 over jj (64KB)

  const int tid = threadIdx.x;
  const int jg = tid >> 6;  // wave id, selects 4 j-rows
  const int ks = tid & 63;  // lane id, selects 16 k's (4 float4, stride 256)
  const int b0 = (blockIdx.x >> 6) * 16;
  const int j0 = (blockIdx.x & 63) * 16;
  const int jbase = j0 + jg * 4;

  // --- W fragment into registers (16 float4) ---
  float4 w[4][4];
#pragma unroll
  for (int jj = 0; jj < 4; ++jj) {
    const float* wr = Whh + (jbase + jj) * HIDDEN + ks * 4;
#pragma unroll
    for (int q = 0; q < 4; ++q)
      w[jj][q] = *reinterpret_cast<const float4*>(wr + 256 * q);
  }

  // --- main loop: 16 batches, 64 FMAs each, h from global ---
  float4 acc[16];
#pragma unroll
  for (int bl = 0; bl < 16; ++bl) {
    const float* hr = h_in + (b0 + bl) * HIDDEN + ks * 4;
    const float4 h0q = *reinterpret_cast<const float4*>(hr);
    const float4 h1q = *reinterpret_cast<const float4*>(hr + 256);
    const float4 h2q = *reinterpret_cast<const float4*>(hr + 512);
    const float4 h3q = *reinterpret_cast<const float4*>(hr + 768);
    float4 a;
    a.x = dot4(w[0][0], h0q) + dot4(w[0][1], h1q) + dot4(w[0][2], h2q) + dot4(w[0][3], h3q);
    a.y = dot4(w[1][0], h0q) + dot4(w[1][1], h1q) + dot4(w[1][2], h2q) + dot4(w[1][3], h3q);
    a.z = dot4(w[2][0], h0q) + dot4(w[2][1], h1q) + dot4(w[2][2], h2q) + dot4(w[2][3], h3q);
    a.w = dot4(w[3][0], h0q) + dot4(w[3][1], h1q) + dot4(w[3][2], h2q) + dot4(w[3][3], h3q);
    acc[bl] = a;
  }

  // --- partials to LDS: [jg][bl][ks], float4 over jj. Lanes consecutive -> no conflict ---
#pragma unroll
  for (int bl = 0; bl < 16; ++bl)
    part[(jg * 16 + bl) * 64 + ks] = acc[bl];
  __syncthreads();

  // --- wave 0 finishes: 64 tasks = (jg', bl') ---
  if (tid < 64) {
    const int fjg = tid >> 4;
    const int fbl = tid & 15;
    const float4* p = part + (fjg * 16 + fbl) * 64;
    float4 ssum = make_float4(0.f, 0.f, 0.f, 0.f);
#pragma unroll 8
    for (int i = 0; i < 64; ++i) {
      const float4 v = p[(i + tid) & 63];  // lane-rotated: even bank coverage
      ssum.x += v.x; ssum.y += v.y; ssum.z += v.z; ssum.w += v.w;
    }
    const int b = b0 + fbl;
    const int c = t[b * SEQ + s];
    const float4 pq = *reinterpret_cast<const float4*>(P + c * HIDDEN + j0 + fjg * 4);
    float4 ho;
    ho.x = tanhf(pq.x + ssum.x);
    ho.y = tanhf(pq.y + ssum.y);
    ho.z = tanhf(pq.z + ssum.z);
    ho.w = tanhf(pq.w + ssum.w);
    *reinterpret_cast<float4*>(h_out + b * HIDDEN + j0 + fjg * 4) = ho;
  }
}

// ---------------------------------------------------------------------------
// out[b][c] = sum_k h[b][k] * W_proj[c][k] + b_proj[c]
// ---------------------------------------------------------------------------
__global__ void outk(const float* __restrict__ h, const float* __restrict__ Wp,
                     const float* __restrict__ bp, float* __restrict__ out) {
  __shared__ float hb[HIDDEN];
  const int b = blockIdx.x;
  const int c = threadIdx.x;
  for (int i = threadIdx.x; i < HIDDEN / 4; i += blockDim.x) {
    reinterpret_cast<float4*>(hb)[i] =
        reinterpret_cast<const float4*>(h + b * HIDDEN)[i];
  }
  __syncthreads();
  const float4* w = reinterpret_cast<const float4*>(Wp + c * HIDDEN);
  float acc = 0.f;
#pragma unroll 8
  for (int k4 = 0; k4 < HIDDEN / 4; ++k4)
    acc += dot4(w[k4], reinterpret_cast<const float4*>(hb)[k4]);
  out[b * N_CHAR + c] = acc + bp[c];
}

// ---------------------------------------------------------------------------
extern "C" void kernel_launch(void* const* d_in, const int* in_sizes, int n_in,
                              void* d_out, int out_size, void* d_ws, size_t ws_size,
                              hipStream_t stream) {
  const int*   t   = (const int*)d_in[0];
  const float* emb = (const float*)d_in[1];
  const float* Wih = (const float*)d_in[2];
  const float* Whh = (const float*)d_in[3];
  const float* h0v = (const float*)d_in[4];
  const float* Wp  = (const float*)d_in[5];
  const float* bp  = (const float*)d_in[6];
  float* out = (float*)d_out;

  float* P  = (float*)d_ws;                 // 128*1024
  float* ha = P + N_CHAR * HIDDEN;          // 64*1024
  float* hb = ha + BATCH * HIDDEN;          // 64*1024

  pk<<<512, 256, 0, stream>>>(emb, Wih, P);
  initk<<<(BATCH * HIDDEN) / 256, 256, 0, stream>>>(h0v, ha);

  float* bufs[2] = {ha, hb};
  for (int s = 0; s < SEQ; ++s) {
    stepk<<<256, 256, 0, stream>>>(bufs[s & 1], bufs[(s + 1) & 1], Whh, P, t, s);
  }
  outk<<<BATCH, 128, 0, stream>>>(bufs[0], Wp, bp, out);
}